// Round 15
// baseline (1032.258 us; speedup 1.0000x reference)
//
#include <hip/hip_runtime.h>
#include <hip/hip_bf16.h>
#include <math.h>

typedef float f4 __attribute__((ext_vector_type(4)));
typedef float f32x4 __attribute__((ext_vector_type(4)));
typedef _Float16 h4 __attribute__((ext_vector_type(4)));
typedef _Float16 h8 __attribute__((ext_vector_type(8)));

#define D_ 1024
#define DFF_ 4096
#define L_ 2
#define RF_ 16
#define NTOK_ 1152            // B * NC = 32*36
#define M_ 18432              // NTOK_ * RF_
#define XROWS_ 1280           // 1152 att rows + 16 rfq rows + s + b + pad

__device__ __forceinline__ void gload_lds16(const void* g, void* l) {
  __builtin_amdgcn_global_load_lds((const __attribute__((address_space(1))) void*)g,
                                   (__attribute__((address_space(3))) void*)l, 16, 0, 0);
}

// exact-GELU via A&S 7.1.26 erf poly (|err| <= 1.5e-7)
__device__ __forceinline__ float gelu_f(float x) {
  float z = fabsf(x) * 0.70710678118654752f;
  float t = 1.0f / (1.0f + 0.3275911f * z);
  float poly = t * (0.254829592f + t * (-0.284496736f + t * (1.421413741f +
               t * (-1.453152027f + t * 1.061405429f))));
  float erfz = 1.0f - poly * __expf(-z * z);
  erfz = copysignf(erfz, x);
  return 0.5f * x * (1.0f + erfz);
}

// ---------------- elementwise ----------------
__global__ __launch_bounds__(256) void k_cvt(const float* __restrict__ in, _Float16* __restrict__ out) {
  int i = blockIdx.x * 256 + threadIdx.x;
  f4 v = ((const f4*)in)[i];
  ((h4*)out)[i] = __builtin_convertvector(v, h4);
}

// X rows: 0..1151 att[n]*s, 1152..1167 rfq[r]*s, 1168 s, 1169 b, rest 0
__global__ __launch_bounds__(256) void k_build_X(const float* __restrict__ att, const float* __restrict__ rfq,
                                                 const float* __restrict__ s, const float* __restrict__ b,
                                                 _Float16* __restrict__ X) {
  int i = blockIdx.x * 256 + threadIdx.x;
  int c = i & 255;
  int row = i >> 8;
  f4 sv = ((const f4*)s)[c];
  f4 v;
  if (row < 1152)      v = ((const f4*)att)[(row << 8) | c] * sv;
  else if (row < 1168) v = ((const f4*)rfq)[((row - 1152) << 8) | c] * sv;
  else if (row == 1168) v = sv;
  else if (row == 1169) v = ((const f4*)b)[c];
  else                 v = (f4){0.f, 0.f, 0.f, 0.f};
  ((h4*)X)[i] = __builtin_convertvector(v, h4);
}

// W (R x C, f32, row-major) -> WT (C x R, f16)
__global__ __launch_bounds__(256) void k_transpose_cvt(const float* __restrict__ W, _Float16* __restrict__ WT,
                                                       int R, int C) {
  __shared__ float t[32][33];
  int c0 = blockIdx.x * 32, r0 = blockIdx.y * 32;
  int cc = threadIdx.x & 31, rr = threadIdx.x >> 5;
  #pragma unroll
  for (int p = 0; p < 32; p += 8)
    t[rr + p][cc] = W[(size_t)(r0 + rr + p) * C + (c0 + cc)];
  __syncthreads();
  #pragma unroll
  for (int p = 0; p < 32; p += 8)
    WT[(size_t)(c0 + rr + p) * R + (r0 + cc)] = (_Float16)t[cc][rr + p];
}

// ---------------- reductions ----------------
__device__ inline float block_sum256(float v) {
  __shared__ float red[4];
  #pragma unroll
  for (int o = 32; o > 0; o >>= 1) v += __shfl_down(v, o);
  int w = threadIdx.x >> 6;
  if ((threadIdx.x & 63) == 0) red[w] = v;
  __syncthreads();
  float r = red[0] + red[1] + red[2] + red[3];
  __syncthreads();
  return r;
}

__global__ __launch_bounds__(256) void k_scal_n(const float* __restrict__ att, const float* __restrict__ rfq,
                                                float* __restrict__ out) {
  int n = blockIdx.x;
  int t = threadIdx.x;
  f4 av = ((const f4*)(att + (size_t)n * D_))[t];
  float s1 = block_sum256(av.x + av.y + av.z + av.w);
  float s2 = block_sum256(av.x*av.x + av.y*av.y + av.z*av.z + av.w*av.w);
  if (t == 0) { out[n*24+0] = s1; out[n*24+1] = s2; }
  #pragma unroll
  for (int r = 0; r < RF_; ++r) {
    f4 qv = ((const f4*)(rfq + (size_t)r * D_))[t];
    float d = block_sum256(av.x*qv.x + av.y*qv.y + av.z*qv.z + av.w*qv.w);
    if (t == 0) out[n*24+2+r] = d;
  }
}

__global__ __launch_bounds__(256) void k_scal_q(const float* __restrict__ rfq, float* __restrict__ out) {
  int r = blockIdx.x;
  int t = threadIdx.x;
  f4 qv = ((const f4*)(rfq + (size_t)r * D_))[t];
  float s1 = block_sum256(qv.x + qv.y + qv.z + qv.w);
  float s2 = block_sum256(qv.x*qv.x + qv.y*qv.y + qv.z*qv.z + qv.w*qv.w);
  if (t == 0) { out[r*2+0] = s1; out[r*2+1] = s2; }
}

// H1[blk,:] = gelu( rstd*(P_a[n] + P_q[r] - mu*P_s) + P_b + b1 ), m=m0+blk
// H1 written non-temporally (single-use stream; keep L3 for operand panels)
__global__ __launch_bounds__(256) void k_combine_gelu(const float* __restrict__ P,
                                                      const float* __restrict__ scn,
                                                      const float* __restrict__ scq,
                                                      const float* __restrict__ b1,
                                                      _Float16* __restrict__ H1, int m0) {
  int m = m0 + blockIdx.x;
  int n = m >> 4, r = m & 15;
  float Sa = scn[n*24+0], Saa = scn[n*24+1], dq = scn[n*24+2+r];
  float Sq = scq[r*2+0], Sqq = scq[r*2+1];
  float mu  = (Sa + Sq) * (1.0f / D_);
  float ex2 = (Saa + 2.0f*dq + Sqq) * (1.0f / D_);
  float rstd = rsqrtf(ex2 - mu*mu + 1e-5f);
  const f4* Pa = (const f4*)(P + (size_t)n * DFF_);
  const f4* Pq = (const f4*)(P + (size_t)(1152 + r) * DFF_);
  const f4* Ps = (const f4*)(P + (size_t)1168 * DFF_);
  const f4* Pb = (const f4*)(P + (size_t)1169 * DFF_);
  const f4* B1 = (const f4*)b1;
  h4* out = (h4*)(H1 + (size_t)blockIdx.x * DFF_);
  #pragma unroll
  for (int it = 0; it < 4; ++it) {
    int j = threadIdx.x + (it << 8);
    f4 hp = (Pa[j] + Pq[j] - mu * Ps[j]) * rstd + Pb[j] + B1[j];
    h4 o;
    o.x = (_Float16)gelu_f(hp.x); o.y = (_Float16)gelu_f(hp.y);
    o.z = (_Float16)gelu_f(hp.z); o.w = (_Float16)gelu_f(hp.w);
    __builtin_nontemporal_store(o, &out[j]);
  }
}

// ---------------- layernorm ----------------
template<int F16OUT>
__global__ __launch_bounds__(256) void k_ln(const float* __restrict__ x, const float* __restrict__ s,
                                            const float* __restrict__ b, void* __restrict__ out) {
  size_t row = blockIdx.x;
  int t = threadIdx.x;
  f4 v = ((const f4*)(x + row * D_))[t];
  float mean = block_sum256(v.x + v.y + v.z + v.w) * (1.0f / D_);
  f4 d = v - mean;
  float var = block_sum256(d.x*d.x + d.y*d.y + d.z*d.z + d.w*d.w) * (1.0f / D_);
  float rstd = rsqrtf(var + 1e-5f);
  f4 sc = ((const f4*)s)[t];
  f4 bb = ((const f4*)b)[t];
  f4 r = d * rstd * sc + bb;
  if (F16OUT) ((h4*)out)[row * (D_/4) + t] = __builtin_convertvector(r, h4);
  else        ((f4*)out)[row * (D_/4) + t] = r;
}

// fused: x_row += att[(m0+row)>>4]; write back; hh = LN(x_row) in f16
__global__ __launch_bounds__(256) void k_ln_add(float* __restrict__ x, const float* __restrict__ att,
                                                const float* __restrict__ s, const float* __restrict__ b,
                                                _Float16* __restrict__ hh, int m0) {
  int blk = blockIdx.x;
  int n = (m0 + blk) >> 4;
  int t = threadIdx.x;
  f4 v = ((const f4*)(x + (size_t)blk * D_))[t] + ((const f4*)(att + (size_t)n * D_))[t];
  ((f4*)(x + (size_t)blk * D_))[t] = v;
  float mean = block_sum256(v.x + v.y + v.z + v.w) * (1.0f / D_);
  f4 d = v - mean;
  float var = block_sum256(d.x*d.x + d.y*d.y + d.z*d.z + d.w*d.w) * (1.0f / D_);
  float rstd = rsqrtf(var + 1e-5f);
  f4 sc = ((const f4*)s)[t];
  f4 bb = ((const f4*)b)[t];
  f4 r = d * rstd * sc + bb;
  ((h4*)hh)[(size_t)blk * (D_/4) + t] = __builtin_convertvector(r, h4);
}

// ---------------- GEMM 128^2, BK=64, 4 blocks/CU (winning config, rounds 13/14) ----------------
// EPI: 0 f16, 1 f32, 2 gelu f16 (NT store), 3 += f32, 4 f32 no-bias,
//      5 f32 = v + bias + att0[n] + rfq[r]   (layer-0 residual fusion; reg-capped by lb(256,4))
template<int EPI, int K, int N, int MINB>
__global__ __launch_bounds__(256, MINB) void k_gemm(const _Float16* __restrict__ A,
                                                    const _Float16* __restrict__ Bt,
                                                    const float* __restrict__ bias,
                                                    void* __restrict__ out,
                                                    size_t sAz, size_t sBz, size_t sBiasz, size_t sOutz,
                                                    const float* __restrict__ attp,
                                                    const float* __restrict__ rfqp, int m0) {
  __shared__ __align__(16) _Float16 As[128][64];
  __shared__ __align__(16) _Float16 Bs[128][64];
  const int tid = threadIdx.x;
  const int lane = tid & 63;
  const int w = tid >> 6;
  const int z = blockIdx.z;
  A += (size_t)z * sAz;
  Bt += (size_t)z * sBz;
  if (EPI != 4) bias += (size_t)z * sBiasz;

  const unsigned gdx = gridDim.x;
  const unsigned nwg = gdx * gridDim.y;
  unsigned bid = blockIdx.y * gdx + blockIdx.x;
  if ((nwg & 7u) == 0u) bid = (bid & 7u) * (nwg >> 3) + (bid >> 3);
  const int bm = (int)(bid / gdx) << 7;
  const int bn = (int)(bid % gdx) << 7;

  const int wr = (w >> 1) << 6;
  const int wc = (w & 1) << 6;
  const int g = lane >> 4;
  const int lr = lane & 15;
  const int x7 = lr & 7;
  const int srow = lane >> 3;
  const int scl8 = (((lane & 7) ^ (srow & 7)) << 3);
  const int c8a = ((0 + g) ^ x7) << 3;
  const int c8b = ((4 + g) ^ x7) << 3;

  f32x4 acc[4][4];
  #pragma unroll
  for (int m = 0; m < 4; ++m)
    #pragma unroll
    for (int n = 0; n < 4; ++n)
      acc[m][n] = (f32x4){0.f, 0.f, 0.f, 0.f};

  const _Float16* gA = A + (size_t)(bm + (w << 5) + srow) * K + scl8;
  const _Float16* gB = Bt + (size_t)(bn + (w << 5) + srow) * K + scl8;

  for (int kt = 0; kt < K; kt += 64) {
    #pragma unroll
    for (int p = 0; p < 4; ++p) {
      const int r0 = (w << 5) + (p << 3);
      gload_lds16(gA + p * (K << 3), &As[r0][0]);
      gload_lds16(gB + p * (K << 3), &Bs[r0][0]);
    }
    gA += 64; gB += 64;
    __syncthreads();
    #pragma unroll
    for (int s2 = 0; s2 < 2; ++s2) {
      const int c8 = s2 ? c8b : c8a;
      h8 af[4], bf[4];
      #pragma unroll
      for (int m = 0; m < 4; ++m) af[m] = *(const h8*)(&As[wr + (m << 4) + lr][c8]);
      #pragma unroll
      for (int n = 0; n < 4; ++n) bf[n] = *(const h8*)(&Bs[wc + (n << 4) + lr][c8]);
      #pragma unroll
      for (int m = 0; m < 4; ++m)
        #pragma unroll
        for (int n = 0; n < 4; ++n)
          acc[m][n] = __builtin_amdgcn_mfma_f32_16x16x32_f16(af[m], bf[n], acc[m][n], 0, 0, 0);
    }
    __syncthreads();
  }

  #pragma unroll
  for (int n = 0; n < 4; ++n) {
    int col = bn + wc + (n << 4) + lr;
    float bval = (EPI == 4) ? 0.0f : bias[col];
    #pragma unroll
    for (int m = 0; m < 4; ++m) {
      #pragma unroll
      for (int j = 0; j < 4; ++j) {
        int row = bm + wr + (m << 4) + (g << 2) + j;   // C/D: col=lane&15, row=(lane>>4)*4+j
        float v = acc[m][n][j] + bval;
        size_t off = (size_t)row * N + col;
        if constexpr (EPI == 0)      ((_Float16*)out + (size_t)z * sOutz)[off] = (_Float16)v;
        else if constexpr (EPI == 1) ((float*)out + (size_t)z * sOutz)[off] = v;
        else if constexpr (EPI == 2) {
          _Float16 gv = (_Float16)gelu_f(v);
          __builtin_nontemporal_store(gv, &((_Float16*)out + (size_t)z * sOutz)[off]);
        }
        else if constexpr (EPI == 3) ((float*)out + (size_t)z * sOutz)[off] += v;
        else if constexpr (EPI == 4) ((float*)out + (size_t)z * sOutz)[off] = v;
        else {                                          // EPI 5: layer-0 residual fusion
          int gm = m0 + row;
          ((float*)out)[off] = v + attp[(size_t)(gm >> 4) * D_ + col]
                                 + rfqp[(size_t)(gm & 15) * D_ + col];
        }
      }
    }
  }
}

// ---------------- launch ----------------
extern "C" void kernel_launch(void* const* d_in, const int* in_sizes, int n_in,
                              void* d_out, int out_size, void* d_ws, size_t ws_size,
                              hipStream_t stream) {
  const float* ct   = (const float*)d_in[0];
  const float* rfq  = (const float*)d_in[1];
  // d_in[2..7]: ln1_s, ln1_b, wq, bq, wk, bk -- dead (softmax over kv_len=1 is identically 1)
  const float* wv   = (const float*)d_in[8];
  const float* bv   = (const float*)d_in[9];
  const float* wo   = (const float*)d_in[10];
  const float* bo   = (const float*)d_in[11];
  const float* ln2s = (const float*)d_in[12];
  const float* ln2b = (const float*)d_in[13];
  const float* w1   = (const float*)d_in[14];
  const float* b1   = (const float*)d_in[15];
  const float* w2   = (const float*)d_in[16];
  const float* b2   = (const float*)d_in[17];
  const float* lnfs = (const float*)d_in[18];
  const float* lnfb = (const float*)d_in[19];

  float* x = (float*)d_out;   // fp32 residual stream in d_out; final LN in-place

  // ---- workspace ----
  char* p = (char*)d_ws;
  auto alloc = [&](size_t bytes) { char* r = p; p += (bytes + 255) & ~(size_t)255; return r; };
  _Float16* kvh = (_Float16*)alloc((size_t)NTOK_ * D_ * 2);
  _Float16* Vh  = (_Float16*)alloc((size_t)L_ * NTOK_ * D_ * 2);   // both layers
  float*    att = (float*)   alloc((size_t)L_ * NTOK_ * D_ * 4);   // both layers
  _Float16* wvt = (_Float16*)alloc((size_t)L_ * D_ * D_ * 2);      // both layers upfront
  _Float16* wot = (_Float16*)alloc((size_t)L_ * D_ * D_ * 2);
  _Float16* w1t = (_Float16*)alloc((size_t)D_ * DFF_ * 2);         // per-layer, reused
  _Float16* w2t = (_Float16*)alloc((size_t)DFF_ * D_ * 2);
  _Float16* Xh  = (_Float16*)alloc((size_t)XROWS_ * D_ * 2);
  float*    P   = (float*)   alloc((size_t)XROWS_ * DFF_ * 4);
  float*    scn = (float*)   alloc((size_t)NTOK_ * 24 * 4);
  float*    scq = (float*)   alloc((size_t)RF_ * 2 * 4);
  size_t persist = (size_t)(p - (char*)d_ws);

  int MC = 1152;
  const int cand[4] = {9216, 4608, 2304, 1152};
  for (int i = 0; i < 4; ++i) {
    size_t need = persist + ((size_t)cand[i] * D_ * 2 + 256) + ((size_t)cand[i] * DFF_ * 2 + 256) + 1024;
    if (need <= ws_size) { MC = cand[i]; break; }
  }
  _Float16* hh  = (_Float16*)alloc((size_t)MC * D_ * 2);
  _Float16* H1h = (_Float16*)alloc((size_t)MC * DFF_ * 2);

  k_cvt<<<NTOK_ * D_ / 4 / 256, 256, 0, stream>>>(ct, kvh);

  // attention for BOTH layers upfront (kv is layer-invariant), batched over blockIdx.z
  for (int l = 0; l < L_; ++l) {
    k_transpose_cvt<<<dim3(D_/32, D_/32), 256, 0, stream>>>(wv + (size_t)l*D_*D_, wvt + (size_t)l*D_*D_, D_, D_);
    k_transpose_cvt<<<dim3(D_/32, D_/32), 256, 0, stream>>>(wo + (size_t)l*D_*D_, wot + (size_t)l*D_*D_, D_, D_);
  }
  k_gemm<0,1024,1024,4><<<dim3(D_/128, NTOK_/128, L_), 256, 0, stream>>>(
      kvh, wvt, bv, Vh, 0, (size_t)D_*D_, D_, (size_t)NTOK_*D_, nullptr, nullptr, 0);
  k_gemm<1,1024,1024,4><<<dim3(D_/128, NTOK_/128, L_), 256, 0, stream>>>(
      Vh, wot, bo, att, (size_t)NTOK_*D_, (size_t)D_*D_, D_, (size_t)NTOK_*D_, nullptr, nullptr, 0);

  for (int l = 0; l < L_; ++l) {
    const float* attl = att + (size_t)l * NTOK_ * D_;
    k_transpose_cvt<<<dim3(DFF_/32, D_/32), 256, 0, stream>>>(w1 + (size_t)l*D_*DFF_, w1t, D_, DFF_);
    k_transpose_cvt<<<dim3(D_/32, DFF_/32), 256, 0, stream>>>(w2 + (size_t)l*DFF_*D_, w2t, DFF_, D_);

    if (l == 0) {
      // x[n,r] = att0[n] + rfq[r] EXACTLY; LN+gemm1 decomposes:
      // h@w1+b1 = rstd[n,r]*(P_a[n] + P_q[r] - mu[n,r]*P_s) + P_b + b1
      k_build_X<<<XROWS_ * D_ / 4 / 256, 256, 0, stream>>>(attl, rfq, ln2s, ln2b, Xh);
      k_scal_n<<<NTOK_, 256, 0, stream>>>(attl, rfq, scn);
      k_scal_q<<<RF_, 256, 0, stream>>>(rfq, scq);
      k_gemm<4,1024,4096,4><<<dim3(DFF_/128, XROWS_/128), 256, 0, stream>>>(
          Xh, w1t, nullptr, P, 0, 0, 0, 0, nullptr, nullptr, 0);
      for (int m0 = 0; m0 < M_; m0 += MC) {
        k_combine_gelu<<<MC, 256, 0, stream>>>(P, scn, scq, b1, H1h, m0);
        // EPI5: x = mlp + b2 + att0[n] + rfq[r]  (residual init fused into epilogue)
        k_gemm<5,4096,1024,4><<<dim3(D_/128, MC/128), 256, 0, stream>>>(
            H1h, w2t, b2, x + (size_t)m0 * D_, 0, 0, 0, 0, attl, rfq, m0);
      }
    } else {
      for (int m0 = 0; m0 < M_; m0 += MC) {
        k_ln_add<<<MC, 256, 0, stream>>>(x + (size_t)m0 * D_, attl, ln2s + l*D_, ln2b + l*D_, hh, m0);
        k_gemm<2,1024,4096,4><<<dim3(DFF_/128, MC/128), 256, 0, stream>>>(
            hh, w1t, b1 + l*DFF_, H1h, 0, 0, 0, 0, nullptr, nullptr, 0);
        k_gemm<3,4096,1024,4><<<dim3(D_/128, MC/128), 256, 0, stream>>>(
            H1h, w2t, b2 + l*D_, x + (size_t)m0 * D_, 0, 0, 0, 0, nullptr, nullptr, 0);
      }
    }
  }
  k_ln<0><<<M_, 256, 0, stream>>>(x, lnfs, lnfb, d_out);
}

// Round 16
// 994.997 us; speedup vs baseline: 1.0374x; 1.0374x over previous
//
#include <hip/hip_runtime.h>
#include <hip/hip_bf16.h>
#include <math.h>

typedef float f4 __attribute__((ext_vector_type(4)));
typedef float f32x4 __attribute__((ext_vector_type(4)));
typedef _Float16 h4 __attribute__((ext_vector_type(4)));
typedef _Float16 h8 __attribute__((ext_vector_type(8)));

#define D_ 1024
#define DFF_ 4096
#define L_ 2
#define RF_ 16
#define NTOK_ 1152            // B * NC = 32*36
#define M_ 18432              // NTOK_ * RF_
#define XROWS_ 1280           // 1152 att rows + 16 rfq rows + s + b + pad

__device__ __forceinline__ void gload_lds16(const void* g, void* l) {
  __builtin_amdgcn_global_load_lds((const __attribute__((address_space(1))) void*)g,
                                   (__attribute__((address_space(3))) void*)l, 16, 0, 0);
}

// exact-GELU via A&S 7.1.26 erf poly (|err| <= 1.5e-7)
__device__ __forceinline__ float gelu_f(float x) {
  float z = fabsf(x) * 0.70710678118654752f;
  float t = 1.0f / (1.0f + 0.3275911f * z);
  float poly = t * (0.254829592f + t * (-0.284496736f + t * (1.421413741f +
               t * (-1.453152027f + t * 1.061405429f))));
  float erfz = 1.0f - poly * __expf(-z * z);
  erfz = copysignf(erfz, x);
  return 0.5f * x * (1.0f + erfz);
}

// ---------------- elementwise ----------------
__global__ __launch_bounds__(256) void k_cvt(const float* __restrict__ in, _Float16* __restrict__ out) {
  int i = blockIdx.x * 256 + threadIdx.x;
  f4 v = ((const f4*)in)[i];
  ((h4*)out)[i] = __builtin_convertvector(v, h4);
}

// X rows: 0..1151 att[n]*s, 1152..1167 rfq[r]*s, 1168 s, 1169 b, rest 0
__global__ __launch_bounds__(256) void k_build_X(const float* __restrict__ att, const float* __restrict__ rfq,
                                                 const float* __restrict__ s, const float* __restrict__ b,
                                                 _Float16* __restrict__ X) {
  int i = blockIdx.x * 256 + threadIdx.x;
  int c = i & 255;
  int row = i >> 8;
  f4 sv = ((const f4*)s)[c];
  f4 v;
  if (row < 1152)      v = ((const f4*)att)[(row << 8) | c] * sv;
  else if (row < 1168) v = ((const f4*)rfq)[((row - 1152) << 8) | c] * sv;
  else if (row == 1168) v = sv;
  else if (row == 1169) v = ((const f4*)b)[c];
  else                 v = (f4){0.f, 0.f, 0.f, 0.f};
  ((h4*)X)[i] = __builtin_convertvector(v, h4);
}

// W (R x C, f32, row-major) -> WT (C x R, f16)
__global__ __launch_bounds__(256) void k_transpose_cvt(const float* __restrict__ W, _Float16* __restrict__ WT,
                                                       int R, int C) {
  __shared__ float t[32][33];
  int c0 = blockIdx.x * 32, r0 = blockIdx.y * 32;
  int cc = threadIdx.x & 31, rr = threadIdx.x >> 5;
  #pragma unroll
  for (int p = 0; p < 32; p += 8)
    t[rr + p][cc] = W[(size_t)(r0 + rr + p) * C + (c0 + cc)];
  __syncthreads();
  #pragma unroll
  for (int p = 0; p < 32; p += 8)
    WT[(size_t)(c0 + rr + p) * R + (r0 + cc)] = (_Float16)t[cc][rr + p];
}

// ---------------- reductions ----------------
__device__ inline float block_sum256(float v) {
  __shared__ float red[4];
  #pragma unroll
  for (int o = 32; o > 0; o >>= 1) v += __shfl_down(v, o);
  int w = threadIdx.x >> 6;
  if ((threadIdx.x & 63) == 0) red[w] = v;
  __syncthreads();
  float r = red[0] + red[1] + red[2] + red[3];
  __syncthreads();
  return r;
}

__global__ __launch_bounds__(256) void k_scal_n(const float* __restrict__ att, const float* __restrict__ rfq,
                                                float* __restrict__ out) {
  int n = blockIdx.x;
  int t = threadIdx.x;
  f4 av = ((const f4*)(att + (size_t)n * D_))[t];
  float s1 = block_sum256(av.x + av.y + av.z + av.w);
  float s2 = block_sum256(av.x*av.x + av.y*av.y + av.z*av.z + av.w*av.w);
  if (t == 0) { out[n*24+0] = s1; out[n*24+1] = s2; }
  #pragma unroll
  for (int r = 0; r < RF_; ++r) {
    f4 qv = ((const f4*)(rfq + (size_t)r * D_))[t];
    float d = block_sum256(av.x*qv.x + av.y*qv.y + av.z*qv.z + av.w*qv.w);
    if (t == 0) out[n*24+2+r] = d;
  }
}

__global__ __launch_bounds__(256) void k_scal_q(const float* __restrict__ rfq, float* __restrict__ out) {
  int r = blockIdx.x;
  int t = threadIdx.x;
  f4 qv = ((const f4*)(rfq + (size_t)r * D_))[t];
  float s1 = block_sum256(qv.x + qv.y + qv.z + qv.w);
  float s2 = block_sum256(qv.x*qv.x + qv.y*qv.y + qv.z*qv.z + qv.w*qv.w);
  if (t == 0) { out[r*2+0] = s1; out[r*2+1] = s2; }
}

// H1[blk,:] = gelu( rstd*(P_a[n] + P_q[r] - mu*P_s) + P_b + b1 ), m=m0+blk;
// fused residual init (round-14 verified): xc[blk,:] = att[n,:] + rfq[r,:]
// H1 written non-temporally (single-use stream) -- the ONE variable vs round 14.
__global__ __launch_bounds__(256) void k_combine_gelu(const float* __restrict__ P,
                                                      const float* __restrict__ scn,
                                                      const float* __restrict__ scq,
                                                      const float* __restrict__ b1,
                                                      _Float16* __restrict__ H1, int m0,
                                                      float* __restrict__ xc,
                                                      const float* __restrict__ att,
                                                      const float* __restrict__ rfq) {
  int m = m0 + blockIdx.x;
  int n = m >> 4, r = m & 15;
  float Sa = scn[n*24+0], Saa = scn[n*24+1], dq = scn[n*24+2+r];
  float Sq = scq[r*2+0], Sqq = scq[r*2+1];
  float mu  = (Sa + Sq) * (1.0f / D_);
  float ex2 = (Saa + 2.0f*dq + Sqq) * (1.0f / D_);
  float rstd = rsqrtf(ex2 - mu*mu + 1e-5f);
  const f4* Pa = (const f4*)(P + (size_t)n * DFF_);
  const f4* Pq = (const f4*)(P + (size_t)(1152 + r) * DFF_);
  const f4* Ps = (const f4*)(P + (size_t)1168 * DFF_);
  const f4* Pb = (const f4*)(P + (size_t)1169 * DFF_);
  const f4* B1 = (const f4*)b1;
  h4* out = (h4*)(H1 + (size_t)blockIdx.x * DFF_);
  #pragma unroll
  for (int it = 0; it < 4; ++it) {
    int j = threadIdx.x + (it << 8);
    f4 hp = (Pa[j] + Pq[j] - mu * Ps[j]) * rstd + Pb[j] + B1[j];
    h4 o;
    o.x = (_Float16)gelu_f(hp.x); o.y = (_Float16)gelu_f(hp.y);
    o.z = (_Float16)gelu_f(hp.z); o.w = (_Float16)gelu_f(hp.w);
    __builtin_nontemporal_store(o, &out[j]);
  }
  int tc = threadIdx.x;
  f4 xv = ((const f4*)(att + (size_t)n * D_))[tc] + ((const f4*)(rfq + (size_t)r * D_))[tc];
  ((f4*)(xc + (size_t)blockIdx.x * D_))[tc] = xv;
}

// ---------------- layernorm ----------------
template<int F16OUT>
__global__ __launch_bounds__(256) void k_ln(const float* __restrict__ x, const float* __restrict__ s,
                                            const float* __restrict__ b, void* __restrict__ out) {
  size_t row = blockIdx.x;
  int t = threadIdx.x;
  f4 v = ((const f4*)(x + row * D_))[t];
  float mean = block_sum256(v.x + v.y + v.z + v.w) * (1.0f / D_);
  f4 d = v - mean;
  float var = block_sum256(d.x*d.x + d.y*d.y + d.z*d.z + d.w*d.w) * (1.0f / D_);
  float rstd = rsqrtf(var + 1e-5f);
  f4 sc = ((const f4*)s)[t];
  f4 bb = ((const f4*)b)[t];
  f4 r = d * rstd * sc + bb;
  if (F16OUT) ((h4*)out)[row * (D_/4) + t] = __builtin_convertvector(r, h4);
  else        ((f4*)out)[row * (D_/4) + t] = r;
}

// fused: x_row += att[(m0+row)>>4]; write back; hh = LN(x_row) in f16
__global__ __launch_bounds__(256) void k_ln_add(float* __restrict__ x, const float* __restrict__ att,
                                                const float* __restrict__ s, const float* __restrict__ b,
                                                _Float16* __restrict__ hh, int m0) {
  int blk = blockIdx.x;
  int n = (m0 + blk) >> 4;
  int t = threadIdx.x;
  f4 v = ((const f4*)(x + (size_t)blk * D_))[t] + ((const f4*)(att + (size_t)n * D_))[t];
  ((f4*)(x + (size_t)blk * D_))[t] = v;
  float mean = block_sum256(v.x + v.y + v.z + v.w) * (1.0f / D_);
  f4 d = v - mean;
  float var = block_sum256(d.x*d.x + d.y*d.y + d.z*d.z + d.w*d.w) * (1.0f / D_);
  float rstd = rsqrtf(var + 1e-5f);
  f4 sc = ((const f4*)s)[t];
  f4 bb = ((const f4*)b)[t];
  f4 r = d * rstd * sc + bb;
  ((h4*)hh)[(size_t)blk * (D_/4) + t] = __builtin_convertvector(r, h4);
}

// ---------------- GEMM 128^2, BK=64, 4 blocks/CU (winning config, rounds 13/14) ----------------
// NO extra global read streams in the epilogue (EPI5 failed twice: rounds 7, 15).
// EPI: 0 f16, 1 f32, 2 gelu f16 (NT store), 3 += f32, 4 f32 no-bias
template<int EPI, int K, int N, int MINB>
__global__ __launch_bounds__(256, MINB) void k_gemm(const _Float16* __restrict__ A,
                                                    const _Float16* __restrict__ Bt,
                                                    const float* __restrict__ bias,
                                                    void* __restrict__ out,
                                                    size_t sAz, size_t sBz, size_t sBiasz, size_t sOutz) {
  __shared__ __align__(16) _Float16 As[128][64];
  __shared__ __align__(16) _Float16 Bs[128][64];
  const int tid = threadIdx.x;
  const int lane = tid & 63;
  const int w = tid >> 6;
  const int z = blockIdx.z;
  A += (size_t)z * sAz;
  Bt += (size_t)z * sBz;
  if (EPI != 4) bias += (size_t)z * sBiasz;

  const unsigned gdx = gridDim.x;
  const unsigned nwg = gdx * gridDim.y;
  unsigned bid = blockIdx.y * gdx + blockIdx.x;
  if ((nwg & 7u) == 0u) bid = (bid & 7u) * (nwg >> 3) + (bid >> 3);
  const int bm = (int)(bid / gdx) << 7;
  const int bn = (int)(bid % gdx) << 7;

  const int wr = (w >> 1) << 6;
  const int wc = (w & 1) << 6;
  const int g = lane >> 4;
  const int lr = lane & 15;
  const int x7 = lr & 7;
  const int srow = lane >> 3;
  const int scl8 = (((lane & 7) ^ (srow & 7)) << 3);
  const int c8a = ((0 + g) ^ x7) << 3;
  const int c8b = ((4 + g) ^ x7) << 3;

  f32x4 acc[4][4];
  #pragma unroll
  for (int m = 0; m < 4; ++m)
    #pragma unroll
    for (int n = 0; n < 4; ++n)
      acc[m][n] = (f32x4){0.f, 0.f, 0.f, 0.f};

  const _Float16* gA = A + (size_t)(bm + (w << 5) + srow) * K + scl8;
  const _Float16* gB = Bt + (size_t)(bn + (w << 5) + srow) * K + scl8;

  for (int kt = 0; kt < K; kt += 64) {
    #pragma unroll
    for (int p = 0; p < 4; ++p) {
      const int r0 = (w << 5) + (p << 3);
      gload_lds16(gA + p * (K << 3), &As[r0][0]);
      gload_lds16(gB + p * (K << 3), &Bs[r0][0]);
    }
    gA += 64; gB += 64;
    __syncthreads();
    #pragma unroll
    for (int s2 = 0; s2 < 2; ++s2) {
      const int c8 = s2 ? c8b : c8a;
      h8 af[4], bf[4];
      #pragma unroll
      for (int m = 0; m < 4; ++m) af[m] = *(const h8*)(&As[wr + (m << 4) + lr][c8]);
      #pragma unroll
      for (int n = 0; n < 4; ++n) bf[n] = *(const h8*)(&Bs[wc + (n << 4) + lr][c8]);
      #pragma unroll
      for (int m = 0; m < 4; ++m)
        #pragma unroll
        for (int n = 0; n < 4; ++n)
          acc[m][n] = __builtin_amdgcn_mfma_f32_16x16x32_f16(af[m], bf[n], acc[m][n], 0, 0, 0);
    }
    __syncthreads();
  }

  #pragma unroll
  for (int n = 0; n < 4; ++n) {
    int col = bn + wc + (n << 4) + lr;
    float bval = (EPI == 4) ? 0.0f : bias[col];
    #pragma unroll
    for (int m = 0; m < 4; ++m) {
      #pragma unroll
      for (int j = 0; j < 4; ++j) {
        int row = bm + wr + (m << 4) + (g << 2) + j;   // C/D: col=lane&15, row=(lane>>4)*4+j
        float v = acc[m][n][j] + bval;
        size_t off = (size_t)row * N + col;
        if constexpr (EPI == 0)      ((_Float16*)out + (size_t)z * sOutz)[off] = (_Float16)v;
        else if constexpr (EPI == 1) ((float*)out + (size_t)z * sOutz)[off] = v;
        else if constexpr (EPI == 2) {
          _Float16 gv = (_Float16)gelu_f(v);
          __builtin_nontemporal_store(gv, &((_Float16*)out + (size_t)z * sOutz)[off]);
        }
        else if constexpr (EPI == 3) ((float*)out + (size_t)z * sOutz)[off] += v;
        else                         ((float*)out + (size_t)z * sOutz)[off] = v;
      }
    }
  }
}

// ---------------- launch ----------------
extern "C" void kernel_launch(void* const* d_in, const int* in_sizes, int n_in,
                              void* d_out, int out_size, void* d_ws, size_t ws_size,
                              hipStream_t stream) {
  const float* ct   = (const float*)d_in[0];
  const float* rfq  = (const float*)d_in[1];
  // d_in[2..7]: ln1_s, ln1_b, wq, bq, wk, bk -- dead (softmax over kv_len=1 is identically 1)
  const float* wv   = (const float*)d_in[8];
  const float* bv   = (const float*)d_in[9];
  const float* wo   = (const float*)d_in[10];
  const float* bo   = (const float*)d_in[11];
  const float* ln2s = (const float*)d_in[12];
  const float* ln2b = (const float*)d_in[13];
  const float* w1   = (const float*)d_in[14];
  const float* b1   = (const float*)d_in[15];
  const float* w2   = (const float*)d_in[16];
  const float* b2   = (const float*)d_in[17];
  const float* lnfs = (const float*)d_in[18];
  const float* lnfb = (const float*)d_in[19];

  float* x = (float*)d_out;   // fp32 residual stream in d_out; final LN in-place

  // ---- workspace ----
  char* p = (char*)d_ws;
  auto alloc = [&](size_t bytes) { char* r = p; p += (bytes + 255) & ~(size_t)255; return r; };
  _Float16* kvh = (_Float16*)alloc((size_t)NTOK_ * D_ * 2);
  _Float16* Vh  = (_Float16*)alloc((size_t)L_ * NTOK_ * D_ * 2);   // both layers
  float*    att = (float*)   alloc((size_t)L_ * NTOK_ * D_ * 4);   // both layers
  _Float16* wvt = (_Float16*)alloc((size_t)L_ * D_ * D_ * 2);      // both layers upfront
  _Float16* wot = (_Float16*)alloc((size_t)L_ * D_ * D_ * 2);
  _Float16* w1t = (_Float16*)alloc((size_t)D_ * DFF_ * 2);         // per-layer, reused
  _Float16* w2t = (_Float16*)alloc((size_t)DFF_ * D_ * 2);
  _Float16* Xh  = (_Float16*)alloc((size_t)XROWS_ * D_ * 2);
  float*    P   = (float*)   alloc((size_t)XROWS_ * DFF_ * 4);
  float*    scn = (float*)   alloc((size_t)NTOK_ * 24 * 4);
  float*    scq = (float*)   alloc((size_t)RF_ * 2 * 4);
  size_t persist = (size_t)(p - (char*)d_ws);

  int MC = 1152;
  const int cand[4] = {9216, 4608, 2304, 1152};
  for (int i = 0; i < 4; ++i) {
    size_t need = persist + ((size_t)cand[i] * D_ * 2 + 256) + ((size_t)cand[i] * DFF_ * 2 + 256) + 1024;
    if (need <= ws_size) { MC = cand[i]; break; }
  }
  _Float16* hh  = (_Float16*)alloc((size_t)MC * D_ * 2);
  _Float16* H1h = (_Float16*)alloc((size_t)MC * DFF_ * 2);

  k_cvt<<<NTOK_ * D_ / 4 / 256, 256, 0, stream>>>(ct, kvh);

  // attention for BOTH layers upfront (kv is layer-invariant), batched over blockIdx.z
  for (int l = 0; l < L_; ++l) {
    k_transpose_cvt<<<dim3(D_/32, D_/32), 256, 0, stream>>>(wv + (size_t)l*D_*D_, wvt + (size_t)l*D_*D_, D_, D_);
    k_transpose_cvt<<<dim3(D_/32, D_/32), 256, 0, stream>>>(wo + (size_t)l*D_*D_, wot + (size_t)l*D_*D_, D_, D_);
  }
  k_gemm<0,1024,1024,4><<<dim3(D_/128, NTOK_/128, L_), 256, 0, stream>>>(
      kvh, wvt, bv, Vh, 0, (size_t)D_*D_, D_, (size_t)NTOK_*D_);
  k_gemm<1,1024,1024,4><<<dim3(D_/128, NTOK_/128, L_), 256, 0, stream>>>(
      Vh, wot, bo, att, (size_t)NTOK_*D_, (size_t)D_*D_, D_, (size_t)NTOK_*D_);

  for (int l = 0; l < L_; ++l) {
    const float* attl = att + (size_t)l * NTOK_ * D_;
    k_transpose_cvt<<<dim3(DFF_/32, D_/32), 256, 0, stream>>>(w1 + (size_t)l*D_*DFF_, w1t, D_, DFF_);
    k_transpose_cvt<<<dim3(D_/32, DFF_/32), 256, 0, stream>>>(w2 + (size_t)l*DFF_*D_, w2t, DFF_, D_);

    if (l == 0) {
      // x[n,r] = att0[n] + rfq[r] EXACTLY; LN+gemm1 decomposes:
      // h@w1+b1 = rstd[n,r]*(P_a[n] + P_q[r] - mu[n,r]*P_s) + P_b + b1
      k_build_X<<<XROWS_ * D_ / 4 / 256, 256, 0, stream>>>(attl, rfq, ln2s, ln2b, Xh);
      k_scal_n<<<NTOK_, 256, 0, stream>>>(attl, rfq, scn);
      k_scal_q<<<RF_, 256, 0, stream>>>(rfq, scq);
      k_gemm<4,1024,4096,4><<<dim3(DFF_/128, XROWS_/128), 256, 0, stream>>>(
          Xh, w1t, nullptr, P, 0, 0, 0, 0);
      for (int m0 = 0; m0 < M_; m0 += MC) {
        // combine also writes x rows m0..m0+MC (fused residual init, round-14 verified)
        k_combine_gelu<<<MC, 256, 0, stream>>>(P, scn, scq, b1, H1h, m0,
                                               x + (size_t)m0 * D_, attl, rfq);
        k_gemm<3,4096,1024,4><<<dim3(D_/128, MC/128), 256, 0, stream>>>(
            H1h, w2t, b2, x + (size_t)m0 * D_, 0, 0, 0, 0);
      }
    } else {
      for (int m0 = 0; m0 < M_; m0 += MC) {
        k_ln_add<<<MC, 256, 0, stream>>>(x + (size_t)m0 * D_, attl, ln2s + l*D_, ln2b + l*D_, hh, m0);
        k_gemm<2,1024,4096,4><<<dim3(DFF_/128, MC/128), 256, 0, stream>>>(
            hh, w1t, b1 + l*DFF_, H1h, 0, 0, 0, 0);
        k_gemm<3,4096,1024,4><<<dim3(D_/128, MC/128), 256, 0, stream>>>(
            H1h, w2t, b2 + l*D_, x + (size_t)m0 * D_, 0, 0, 0, 0);
      }
    }
  }
  k_ln<0><<<M_, 256, 0, stream>>>(x, lnfs, lnfb, d_out);
}

// Round 17
// 844.640 us; speedup vs baseline: 1.2221x; 1.1780x over previous
//
#include <hip/hip_runtime.h>
#include <hip/hip_bf16.h>
#include <math.h>

typedef float f4 __attribute__((ext_vector_type(4)));
typedef float f32x4 __attribute__((ext_vector_type(4)));
typedef _Float16 h4 __attribute__((ext_vector_type(4)));
typedef _Float16 h8 __attribute__((ext_vector_type(8)));

#define D_ 1024
#define DFF_ 4096
#define L_ 2
#define RF_ 16
#define NTOK_ 1152            // B * NC = 32*36
#define M_ 18432              // NTOK_ * RF_
#define XROWS_ 1280           // 1152 att rows + 16 rfq rows + s + b + pad

__device__ __forceinline__ void gload_lds16(const void* g, void* l) {
  __builtin_amdgcn_global_load_lds((const __attribute__((address_space(1))) void*)g,
                                   (__attribute__((address_space(3))) void*)l, 16, 0, 0);
}

// exact-GELU via A&S 7.1.26 erf poly (|err| <= 1.5e-7)
__device__ __forceinline__ float gelu_f(float x) {
  float z = fabsf(x) * 0.70710678118654752f;
  float t = 1.0f / (1.0f + 0.3275911f * z);
  float poly = t * (0.254829592f + t * (-0.284496736f + t * (1.421413741f +
               t * (-1.453152027f + t * 1.061405429f))));
  float erfz = 1.0f - poly * __expf(-z * z);
  erfz = copysignf(erfz, x);
  return 0.5f * x * (1.0f + erfz);
}

// ---------------- elementwise ----------------
__global__ __launch_bounds__(256) void k_cvt(const float* __restrict__ in, _Float16* __restrict__ out) {
  int i = blockIdx.x * 256 + threadIdx.x;
  f4 v = ((const f4*)in)[i];
  ((h4*)out)[i] = __builtin_convertvector(v, h4);
}

// X rows: 0..1151 att[n]*s, 1152..1167 rfq[r]*s, 1168 s, 1169 b, rest 0
__global__ __launch_bounds__(256) void k_build_X(const float* __restrict__ att, const float* __restrict__ rfq,
                                                 const float* __restrict__ s, const float* __restrict__ b,
                                                 _Float16* __restrict__ X) {
  int i = blockIdx.x * 256 + threadIdx.x;
  int c = i & 255;
  int row = i >> 8;
  f4 sv = ((const f4*)s)[c];
  f4 v;
  if (row < 1152)      v = ((const f4*)att)[(row << 8) | c] * sv;
  else if (row < 1168) v = ((const f4*)rfq)[((row - 1152) << 8) | c] * sv;
  else if (row == 1168) v = sv;
  else if (row == 1169) v = ((const f4*)b)[c];
  else                 v = (f4){0.f, 0.f, 0.f, 0.f};
  ((h4*)X)[i] = __builtin_convertvector(v, h4);
}

// W (R x C, f32, row-major) -> WT (C x R, f16); z-batched via sWz stride
__global__ __launch_bounds__(256) void k_transpose_cvt(const float* __restrict__ W, _Float16* __restrict__ WT,
                                                       int R, int C, size_t sWz) {
  __shared__ float t[32][33];
  W += (size_t)blockIdx.z * sWz;
  WT += (size_t)blockIdx.z * sWz;
  int c0 = blockIdx.x * 32, r0 = blockIdx.y * 32;
  int cc = threadIdx.x & 31, rr = threadIdx.x >> 5;
  #pragma unroll
  for (int p = 0; p < 32; p += 8)
    t[rr + p][cc] = W[(size_t)(r0 + rr + p) * C + (c0 + cc)];
  __syncthreads();
  #pragma unroll
  for (int p = 0; p < 32; p += 8)
    WT[(size_t)(c0 + rr + p) * R + (r0 + cc)] = (_Float16)t[cc][rr + p];
}

// ---------------- reductions ----------------
__device__ inline float block_sum256(float v) {
  __shared__ float red[4];
  #pragma unroll
  for (int o = 32; o > 0; o >>= 1) v += __shfl_down(v, o);
  int w = threadIdx.x >> 6;
  if ((threadIdx.x & 63) == 0) red[w] = v;
  __syncthreads();
  float r = red[0] + red[1] + red[2] + red[3];
  __syncthreads();
  return r;
}

__global__ __launch_bounds__(256) void k_scal_n(const float* __restrict__ att, const float* __restrict__ rfq,
                                                float* __restrict__ out) {
  int n = blockIdx.x;
  int t = threadIdx.x;
  f4 av = ((const f4*)(att + (size_t)n * D_))[t];
  float s1 = block_sum256(av.x + av.y + av.z + av.w);
  float s2 = block_sum256(av.x*av.x + av.y*av.y + av.z*av.z + av.w*av.w);
  if (t == 0) { out[n*24+0] = s1; out[n*24+1] = s2; }
  #pragma unroll
  for (int r = 0; r < RF_; ++r) {
    f4 qv = ((const f4*)(rfq + (size_t)r * D_))[t];
    float d = block_sum256(av.x*qv.x + av.y*qv.y + av.z*qv.z + av.w*qv.w);
    if (t == 0) out[n*24+2+r] = d;
  }
}

__global__ __launch_bounds__(256) void k_scal_q(const float* __restrict__ rfq, float* __restrict__ out) {
  int r = blockIdx.x;
  int t = threadIdx.x;
  f4 qv = ((const f4*)(rfq + (size_t)r * D_))[t];
  float s1 = block_sum256(qv.x + qv.y + qv.z + qv.w);
  float s2 = block_sum256(qv.x*qv.x + qv.y*qv.y + qv.z*qv.z + qv.w*qv.w);
  if (t == 0) { out[r*2+0] = s1; out[r*2+1] = s2; }
}

// bvo[z][j] = sum_k bv[z][k]*wo[z][k][j] + bo[z][j] = dot(wot[z] row j, bv[z]) + bo[z][j]
__global__ __launch_bounds__(256) void k_bvo(const _Float16* __restrict__ wot, const float* __restrict__ bv,
                                             const float* __restrict__ bo, float* __restrict__ bvo) {
  int j = blockIdx.x, z = blockIdx.y;
  wot += (size_t)z * D_ * D_;
  bv += (size_t)z * D_; bo += (size_t)z * D_; bvo += (size_t)z * D_;
  int t = threadIdx.x;
  h4 wv4 = ((const h4*)(wot + (size_t)j * D_))[t];
  f4 bv4 = ((const f4*)bv)[t];
  float s = (float)wv4.x*bv4.x + (float)wv4.y*bv4.y + (float)wv4.z*bv4.z + (float)wv4.w*bv4.w;
  s = block_sum256(s);
  if (t == 0) bvo[j] = s + bo[j];
}

// H1[blk,:] = gelu( rstd*(P_a[n] + P_q[r] - mu*P_s) + P_b + b1 ), m=m0+blk;
// fused residual init (round-14 verified): xc[blk,:] = att[n,:] + rfq[r,:]
__global__ __launch_bounds__(256) void k_combine_gelu(const float* __restrict__ P,
                                                      const float* __restrict__ scn,
                                                      const float* __restrict__ scq,
                                                      const float* __restrict__ b1,
                                                      _Float16* __restrict__ H1, int m0,
                                                      float* __restrict__ xc,
                                                      const float* __restrict__ att,
                                                      const float* __restrict__ rfq) {
  int m = m0 + blockIdx.x;
  int n = m >> 4, r = m & 15;
  float Sa = scn[n*24+0], Saa = scn[n*24+1], dq = scn[n*24+2+r];
  float Sq = scq[r*2+0], Sqq = scq[r*2+1];
  float mu  = (Sa + Sq) * (1.0f / D_);
  float ex2 = (Saa + 2.0f*dq + Sqq) * (1.0f / D_);
  float rstd = rsqrtf(ex2 - mu*mu + 1e-5f);
  const f4* Pa = (const f4*)(P + (size_t)n * DFF_);
  const f4* Pq = (const f4*)(P + (size_t)(1152 + r) * DFF_);
  const f4* Ps = (const f4*)(P + (size_t)1168 * DFF_);
  const f4* Pb = (const f4*)(P + (size_t)1169 * DFF_);
  const f4* B1 = (const f4*)b1;
  h4* out = (h4*)(H1 + (size_t)blockIdx.x * DFF_);
  #pragma unroll
  for (int it = 0; it < 4; ++it) {
    int j = threadIdx.x + (it << 8);
    f4 hp = (Pa[j] + Pq[j] - mu * Ps[j]) * rstd + Pb[j] + B1[j];
    h4 o;
    o.x = (_Float16)gelu_f(hp.x); o.y = (_Float16)gelu_f(hp.y);
    o.z = (_Float16)gelu_f(hp.z); o.w = (_Float16)gelu_f(hp.w);
    out[j] = o;
  }
  int tc = threadIdx.x;
  f4 xv = ((const f4*)(att + (size_t)n * D_))[tc] + ((const f4*)(rfq + (size_t)r * D_))[tc];
  ((f4*)(xc + (size_t)blockIdx.x * D_))[tc] = xv;
}

// ---------------- layernorm ----------------
template<int F16OUT>
__global__ __launch_bounds__(256) void k_ln(const float* __restrict__ x, const float* __restrict__ s,
                                            const float* __restrict__ b, void* __restrict__ out) {
  size_t row = blockIdx.x;
  int t = threadIdx.x;
  f4 v = ((const f4*)(x + row * D_))[t];
  float mean = block_sum256(v.x + v.y + v.z + v.w) * (1.0f / D_);
  f4 d = v - mean;
  float var = block_sum256(d.x*d.x + d.y*d.y + d.z*d.z + d.w*d.w) * (1.0f / D_);
  float rstd = rsqrtf(var + 1e-5f);
  f4 sc = ((const f4*)s)[t];
  f4 bb = ((const f4*)b)[t];
  f4 r = d * rstd * sc + bb;
  if (F16OUT) ((h4*)out)[row * (D_/4) + t] = __builtin_convertvector(r, h4);
  else        ((f4*)out)[row * (D_/4) + t] = r;
}

// fused: x_row += att[(m0+row)>>4]; write back; hh = LN(x_row) in f16
__global__ __launch_bounds__(256) void k_ln_add(float* __restrict__ x, const float* __restrict__ att,
                                                const float* __restrict__ s, const float* __restrict__ b,
                                                _Float16* __restrict__ hh, int m0) {
  int blk = blockIdx.x;
  int n = (m0 + blk) >> 4;
  int t = threadIdx.x;
  f4 v = ((const f4*)(x + (size_t)blk * D_))[t] + ((const f4*)(att + (size_t)n * D_))[t];
  ((f4*)(x + (size_t)blk * D_))[t] = v;
  float mean = block_sum256(v.x + v.y + v.z + v.w) * (1.0f / D_);
  f4 d = v - mean;
  float var = block_sum256(d.x*d.x + d.y*d.y + d.z*d.z + d.w*d.w) * (1.0f / D_);
  float rstd = rsqrtf(var + 1e-5f);
  f4 sc = ((const f4*)s)[t];
  f4 bb = ((const f4*)b)[t];
  f4 r = d * rstd * sc + bb;
  ((h4*)hh)[(size_t)blk * (D_/4) + t] = __builtin_convertvector(r, h4);
}

// ---------------- GEMM 128^2, BK=64, 4 blocks/CU (winning config, rounds 13/14) ----------------
// Plain cached stores (NT regressed, round 16). No extra epilogue read streams (EPI5 failed 2x).
// EPI: 0 f16+bias, 1 f32+bias, 2 gelu f16+bias, 3 += f32+bias, 4 f32 no-bias, 6 f16 no-bias
template<int EPI, int K, int N, int MINB>
__global__ __launch_bounds__(256, MINB) void k_gemm(const _Float16* __restrict__ A,
                                                    const _Float16* __restrict__ Bt,
                                                    const float* __restrict__ bias,
                                                    void* __restrict__ out,
                                                    size_t sAz, size_t sBz, size_t sBiasz, size_t sOutz) {
  __shared__ __align__(16) _Float16 As[128][64];
  __shared__ __align__(16) _Float16 Bs[128][64];
  const int tid = threadIdx.x;
  const int lane = tid & 63;
  const int w = tid >> 6;
  const int z = blockIdx.z;
  A += (size_t)z * sAz;
  Bt += (size_t)z * sBz;
  if (EPI != 4 && EPI != 6) bias += (size_t)z * sBiasz;

  const unsigned gdx = gridDim.x;
  const unsigned nwg = gdx * gridDim.y;
  unsigned bid = blockIdx.y * gdx + blockIdx.x;
  if ((nwg & 7u) == 0u) bid = (bid & 7u) * (nwg >> 3) + (bid >> 3);
  const int bm = (int)(bid / gdx) << 7;
  const int bn = (int)(bid % gdx) << 7;

  const int wr = (w >> 1) << 6;
  const int wc = (w & 1) << 6;
  const int g = lane >> 4;
  const int lr = lane & 15;
  const int x7 = lr & 7;
  const int srow = lane >> 3;
  const int scl8 = (((lane & 7) ^ (srow & 7)) << 3);
  const int c8a = ((0 + g) ^ x7) << 3;
  const int c8b = ((4 + g) ^ x7) << 3;

  f32x4 acc[4][4];
  #pragma unroll
  for (int m = 0; m < 4; ++m)
    #pragma unroll
    for (int n = 0; n < 4; ++n)
      acc[m][n] = (f32x4){0.f, 0.f, 0.f, 0.f};

  const _Float16* gA = A + (size_t)(bm + (w << 5) + srow) * K + scl8;
  const _Float16* gB = Bt + (size_t)(bn + (w << 5) + srow) * K + scl8;

  for (int kt = 0; kt < K; kt += 64) {
    #pragma unroll
    for (int p = 0; p < 4; ++p) {
      const int r0 = (w << 5) + (p << 3);
      gload_lds16(gA + p * (K << 3), &As[r0][0]);
      gload_lds16(gB + p * (K << 3), &Bs[r0][0]);
    }
    gA += 64; gB += 64;
    __syncthreads();
    #pragma unroll
    for (int s2 = 0; s2 < 2; ++s2) {
      const int c8 = s2 ? c8b : c8a;
      h8 af[4], bf[4];
      #pragma unroll
      for (int m = 0; m < 4; ++m) af[m] = *(const h8*)(&As[wr + (m << 4) + lr][c8]);
      #pragma unroll
      for (int n = 0; n < 4; ++n) bf[n] = *(const h8*)(&Bs[wc + (n << 4) + lr][c8]);
      #pragma unroll
      for (int m = 0; m < 4; ++m)
        #pragma unroll
        for (int n = 0; n < 4; ++n)
          acc[m][n] = __builtin_amdgcn_mfma_f32_16x16x32_f16(af[m], bf[n], acc[m][n], 0, 0, 0);
    }
    __syncthreads();
  }

  #pragma unroll
  for (int n = 0; n < 4; ++n) {
    int col = bn + wc + (n << 4) + lr;
    float bval = (EPI == 4 || EPI == 6) ? 0.0f : bias[col];
    #pragma unroll
    for (int m = 0; m < 4; ++m) {
      #pragma unroll
      for (int j = 0; j < 4; ++j) {
        int row = bm + wr + (m << 4) + (g << 2) + j;   // C/D: col=lane&15, row=(lane>>4)*4+j
        float v = acc[m][n][j] + bval;
        size_t off = (size_t)row * N + col;
        if constexpr (EPI == 0)      ((_Float16*)out + (size_t)z * sOutz)[off] = (_Float16)v;
        else if constexpr (EPI == 1) ((float*)out + (size_t)z * sOutz)[off] = v;
        else if constexpr (EPI == 2) ((_Float16*)out + (size_t)z * sOutz)[off] = (_Float16)gelu_f(v);
        else if constexpr (EPI == 3) ((float*)out + (size_t)z * sOutz)[off] += v;
        else if constexpr (EPI == 4) ((float*)out + (size_t)z * sOutz)[off] = v;
        else                         ((_Float16*)out + (size_t)z * sOutz)[off] = (_Float16)v;
      }
    }
  }
}

// ---------------- launch ----------------
extern "C" void kernel_launch(void* const* d_in, const int* in_sizes, int n_in,
                              void* d_out, int out_size, void* d_ws, size_t ws_size,
                              hipStream_t stream) {
  const float* ct   = (const float*)d_in[0];
  const float* rfq  = (const float*)d_in[1];
  // d_in[2..7]: ln1_s, ln1_b, wq, bq, wk, bk -- dead (softmax over kv_len=1 is identically 1)
  const float* wv   = (const float*)d_in[8];
  const float* bv   = (const float*)d_in[9];
  const float* wo   = (const float*)d_in[10];
  const float* bo   = (const float*)d_in[11];
  const float* ln2s = (const float*)d_in[12];
  const float* ln2b = (const float*)d_in[13];
  const float* w1   = (const float*)d_in[14];
  const float* b1   = (const float*)d_in[15];
  const float* w2   = (const float*)d_in[16];
  const float* b2   = (const float*)d_in[17];
  const float* lnfs = (const float*)d_in[18];
  const float* lnfb = (const float*)d_in[19];

  float* x = (float*)d_out;   // fp32 residual stream in d_out; final LN in-place

  // ---- workspace ----
  char* p = (char*)d_ws;
  auto alloc = [&](size_t bytes) { char* r = p; p += (bytes + 255) & ~(size_t)255; return r; };
  _Float16* kvh  = (_Float16*)alloc((size_t)NTOK_ * D_ * 2);
  float*    att  = (float*)   alloc((size_t)L_ * NTOK_ * D_ * 4);   // both layers
  _Float16* wvh  = (_Float16*)alloc((size_t)L_ * D_ * D_ * 2);      // wv f16 row-major
  _Float16* wot  = (_Float16*)alloc((size_t)L_ * D_ * D_ * 2);      // wo^T f16
  _Float16* wvoT = (_Float16*)alloc((size_t)L_ * D_ * D_ * 2);      // (wv@wo)^T f16
  float*    bvo  = (float*)   alloc((size_t)L_ * D_ * 4);           // bv@wo + bo
  _Float16* w1t  = (_Float16*)alloc((size_t)D_ * DFF_ * 2);         // per-layer, reused
  _Float16* w2t  = (_Float16*)alloc((size_t)DFF_ * D_ * 2);
  _Float16* Xh   = (_Float16*)alloc((size_t)XROWS_ * D_ * 2);
  float*    P    = (float*)   alloc((size_t)XROWS_ * DFF_ * 4);
  float*    scn  = (float*)   alloc((size_t)NTOK_ * 24 * 4);
  float*    scq  = (float*)   alloc((size_t)RF_ * 2 * 4);
  size_t persist = (size_t)(p - (char*)d_ws);

  int MC = 1152;
  const int cand[4] = {9216, 4608, 2304, 1152};
  for (int i = 0; i < 4; ++i) {
    size_t need = persist + ((size_t)cand[i] * D_ * 2 + 256) + ((size_t)cand[i] * DFF_ * 2 + 256) + 1024;
    if (need <= ws_size) { MC = cand[i]; break; }
  }
  _Float16* hh  = (_Float16*)alloc((size_t)MC * D_ * 2);
  _Float16* H1h = (_Float16*)alloc((size_t)MC * DFF_ * 2);

  // ---- attention collapsed across the token dimension:
  //   att_l = kv @ (wv_l@wo_l) + (bv_l@wo_l + bo_l)   (exact algebra; fp32-accum GEMMs)
  k_cvt<<<NTOK_ * D_ / 4 / 256, 256, 0, stream>>>(ct, kvh);
  k_cvt<<<L_ * D_ * D_ / 4 / 256, 256, 0, stream>>>(wv, wvh);                   // both layers, one launch
  k_transpose_cvt<<<dim3(D_/32, D_/32, L_), 256, 0, stream>>>(wo, wot, D_, D_, (size_t)D_*D_);
  // wvoT[i,j] = sum_k wot[i,k]*wvh[j,k] = wvo^T  (EPI6: f16 no-bias)
  k_gemm<6,1024,1024,4><<<dim3(D_/128, D_/128, L_), 256, 0, stream>>>(
      wot, wvh, nullptr, wvoT, (size_t)D_*D_, (size_t)D_*D_, 0, (size_t)D_*D_);
  k_bvo<<<dim3(D_, L_), 256, 0, stream>>>(wot, bv, bo, bvo);
  // att_l = kv @ wvo_l + bvo_l  (Bt = wvoT)
  k_gemm<1,1024,1024,4><<<dim3(D_/128, NTOK_/128, L_), 256, 0, stream>>>(
      kvh, wvoT, bvo, att, 0, (size_t)D_*D_, D_, (size_t)NTOK_*D_);

  for (int l = 0; l < L_; ++l) {
    const float* attl = att + (size_t)l * NTOK_ * D_;
    k_transpose_cvt<<<dim3(DFF_/32, D_/32), 256, 0, stream>>>(w1 + (size_t)l*D_*DFF_, w1t, D_, DFF_, 0);
    k_transpose_cvt<<<dim3(D_/32, DFF_/32), 256, 0, stream>>>(w2 + (size_t)l*DFF_*D_, w2t, DFF_, D_, 0);

    if (l == 0) {
      // x[n,r] = att0[n] + rfq[r] EXACTLY; LN+gemm1 decomposes:
      // h@w1+b1 = rstd[n,r]*(P_a[n] + P_q[r] - mu[n,r]*P_s) + P_b + b1
      k_build_X<<<XROWS_ * D_ / 4 / 256, 256, 0, stream>>>(attl, rfq, ln2s, ln2b, Xh);
      k_scal_n<<<NTOK_, 256, 0, stream>>>(attl, rfq, scn);
      k_scal_q<<<RF_, 256, 0, stream>>>(rfq, scq);
      k_gemm<4,1024,4096,4><<<dim3(DFF_/128, XROWS_/128), 256, 0, stream>>>(
          Xh, w1t, nullptr, P, 0, 0, 0, 0);
      for (int m0 = 0; m0 < M_; m0 += MC) {
        // combine also writes x rows m0..m0+MC (fused residual init, round-14 verified)
        k_combine_gelu<<<MC, 256, 0, stream>>>(P, scn, scq, b1, H1h, m0,
                                               x + (size_t)m0 * D_, attl, rfq);
        k_gemm<3,4096,1024,4><<<dim3(D_/128, MC/128), 256, 0, stream>>>(
            H1h, w2t, b2, x + (size_t)m0 * D_, 0, 0, 0, 0);
      }
    } else {
      for (int m0 = 0; m0 < M_; m0 += MC) {
        k_ln_add<<<MC, 256, 0, stream>>>(x + (size_t)m0 * D_, attl, ln2s + l*D_, ln2b + l*D_, hh, m0);
        k_gemm<2,1024,4096,4><<<dim3(DFF_/128, MC/128), 256, 0, stream>>>(
            hh, w1t, b1 + l*DFF_, H1h, 0, 0, 0, 0);
        k_gemm<3,4096,1024,4><<<dim3(D_/128, MC/128), 256, 0, stream>>>(
            H1h, w2t, b2 + l*D_, x + (size_t)m0 * D_, 0, 0, 0, 0);
      }
    }
  }
  k_ln<0><<<M_, 256, 0, stream>>>(x, lnfs, lnfb, d_out);
}